// Round 6
// baseline (238.043 us; speedup 1.0000x reference)
//
#include <hip/hip_runtime.h>
#include <hip/hip_bf16.h>
#include <math.h>

#define ROWS 256
#define DD 64
#define EE 8
#define HH 64
#define GHD 32

typedef __attribute__((ext_vector_type(8))) short bf16x8;
typedef __attribute__((ext_vector_type(4))) float f32x4;

static __device__ __forceinline__ short f2bf(float f) {
    unsigned u = __builtin_bit_cast(unsigned, f);
    unsigned r = (u + 0x7fffu + ((u >> 16) & 1u)) >> 16;  // round-to-nearest-even
    return (short)r;
}
// packed f32x2 -> bf16x2 (lowers to v_cvt_pk_bf16_f32, RNE — bit-identical to f2bf)
static __device__ __forceinline__ unsigned pk2(float lo, float hi) {
    __hip_bfloat162 h = __float22bfloat162_rn(make_float2(lo, hi));
    unsigned r;
    __builtin_memcpy(&r, &h, 4);
    return r;
}
// cross-lane add via ds_bpermute (addr = (lane^mask)<<2, precomputed)
static __device__ __forceinline__ float bperm_add(float x, int addr) {
    int xi = __builtin_bit_cast(int, x);
    int yi = __builtin_amdgcn_ds_bpermute(addr, xi);
    return x + __builtin_bit_cast(float, yi);
}

// Precompute W1 (experts) and gw1 (gating) as bf16 MFMA fragments in d_ws.
// For 16x16x32, A-frag and B-frag lane->(index,k) maps are identical, so these
// frags serve as W1 B-operand (x·W1) or W1^T A-operand (W1^T·x^T) unchanged.
// expert frags: idx = wave<<10 | tt<<7 | half<<6 | lane, 8 shorts each (64 KB)
// gating frags (gw1^T A-operand): 2 tiles x 64 lanes x 8 shorts at short-offset 32768 (2 KB)
// d_ws must be >= 67584 bytes.
__global__ __launch_bounds__(256) void prep_kernel(const float* __restrict__ ew1,
                                                   const float* __restrict__ gw1,
                                                   short* __restrict__ wf) {
    int idx = blockIdx.x * 256 + threadIdx.x;   // 4096 frags
    int lane = idx & 63;
    int half = (idx >> 6) & 1;
    int tt   = (idx >> 7) & 7;
    int wave = (idx >> 10) & 3;
    int n = wave * 128 + tt * 16 + (lane & 15);
    int e = n >> 6, h = n & 63;
    int quad = lane >> 4;
    short v[8];
    #pragma unroll
    for (int j = 0; j < 8; ++j) {
        int dl = quad * 8 + j + half * 32;
        v[j] = f2bf(ew1[(e * DD + dl) * HH + h]);
    }
    *(bf16x8*)(wf + (size_t)idx * 8) = *(const bf16x8*)v;
    if (idx < 128) {                            // gw1^T A-frags
        int tile = idx >> 6;
        int lr = lane & 15;
        short g[8];
        #pragma unroll
        for (int j = 0; j < 8; ++j)
            g[j] = f2bf(gw1[(quad * 8 + j) * GHD + tile * 16 + lr]);
        *(bf16x8*)(wf + 32768 + (size_t)idx * 8) = *(const bf16x8*)g;
    }
}

__global__ __launch_bounds__(256, 3) void moe_kernel(
    const float* __restrict__ A, const float* __restrict__ S,
    const float* __restrict__ gb1, const float* __restrict__ gw2,
    const float* __restrict__ gb2, const short* __restrict__ wf,
    const float* __restrict__ eb1, const float* __restrict__ ew2,
    const float* __restrict__ eb2, float* __restrict__ out)
{
    // xs row = 72 shorts (144 B): [0..63] bf16 x-data, [64..71] = 4 f32 result slots (1/wave).
    __shared__ __align__(16) short xs[ROWS][72];            // 36864 B
    __shared__ __align__(16) unsigned short psb[ROWS][EE];  // 4096 B (bf16 gating probs)
    // total 40960 B

    const int t = threadIdx.x;
    const int row0 = blockIdx.x * ROWS;
    const int lane = t & 63;
    const int wave = t >> 6;
    const int quad = lane >> 4;
    const int lr = lane & 15;

    // ---- Phase 1: x -> bf16 LDS (cvt_pk, 1 inst / 2 values) ----
    {
        const int row = row0 + t;
        const float4* ar = (const float4*)(A + (size_t)row * 32);
        const float4* sr = (const float4*)(S + (size_t)row * 32);
        #pragma unroll
        for (int i = 0; i < 4; ++i) {
            float4 v0 = ar[2 * i], v1 = ar[2 * i + 1];
            uint4 u;
            u.x = pk2(v0.x, v0.y); u.y = pk2(v0.z, v0.w);
            u.z = pk2(v1.x, v1.y); u.w = pk2(v1.z, v1.w);
            *(uint4*)&xs[t][i * 8] = u;
        }
        #pragma unroll
        for (int i = 0; i < 4; ++i) {
            float4 v0 = sr[2 * i], v1 = sr[2 * i + 1];
            uint4 u;
            u.x = pk2(v0.x, v0.y); u.y = pk2(v0.z, v0.w);
            u.z = pk2(v1.x, v1.y); u.w = pk2(v1.z, v1.w);
            *(uint4*)&xs[t][32 + i * 8] = u;
        }
    }
    // Wave-local ordering: this wave's 64 lanes wrote rows [wave*64, wave*64+64);
    // gating below reads exactly those rows -> no __syncthreads needed, but the
    // cross-lane LDS writes must drain before any read (rule #18).
    asm volatile("s_waitcnt lgkmcnt(0)" ::: "memory");
    __builtin_amdgcn_sched_barrier(0);

    const int a16 = (lane ^ 16) << 2;
    const int a32 = (lane ^ 32) << 2;

    // ---- Phase 1.5: gating, transposed (gh^T = gw1^T · S^T), register-only ----
    {
        const short* gwf = wf + 32768;
        bf16x8 gf0 = *(const bf16x8*)(gwf + (size_t)lane * 8);         // gw1^T rows g=0..15
        bf16x8 gf1 = *(const bf16x8*)(gwf + 512 + (size_t)lane * 8);   // rows g=16..31
        // per-lane gw2 slice: rows g = quad*4+j (j<4) and 16+quad*4+(j-4) (j>=4)
        float gw2r[8][8];
        #pragma unroll
        for (int j = 0; j < 4; ++j) {
            float4 a0 = *(const float4*)(gw2 + (quad * 4 + j) * 8);
            float4 a1 = *(const float4*)(gw2 + (quad * 4 + j) * 8 + 4);
            gw2r[j][0] = a0.x; gw2r[j][1] = a0.y; gw2r[j][2] = a0.z; gw2r[j][3] = a0.w;
            gw2r[j][4] = a1.x; gw2r[j][5] = a1.y; gw2r[j][6] = a1.z; gw2r[j][7] = a1.w;
            float4 b0 = *(const float4*)(gw2 + (16 + quad * 4 + j) * 8);
            float4 b1 = *(const float4*)(gw2 + (16 + quad * 4 + j) * 8 + 4);
            gw2r[4 + j][0] = b0.x; gw2r[4 + j][1] = b0.y; gw2r[4 + j][2] = b0.z; gw2r[4 + j][3] = b0.w;
            gw2r[4 + j][4] = b1.x; gw2r[4 + j][5] = b1.y; gw2r[4 + j][6] = b1.z; gw2r[4 + j][7] = b1.w;
        }
        const f32x4 binit0 = *(const f32x4*)(gb1 + quad * 4);
        const f32x4 binit1 = *(const f32x4*)(gb1 + 16 + quad * 4);
        // gb2 folded into quad-0's partial init: the xor16/xor32 butterfly
        // distributes the full sum (incl. gb2) to every lane.
        float gb2q[8];
        #pragma unroll
        for (int e = 0; e < 8; ++e) gb2q[e] = (quad == 0) ? gb2[e] : 0.0f;

        // prefetch first S^T fragment
        bf16x8 sb = *(const bf16x8*)&xs[wave * 64 + lr][32 + quad * 8];

        #pragma unroll 1
        for (int i = 0; i < 4; ++i) {
            const int rt = wave * 4 + i;
            // prefetch next iteration's fragment (dep-free, hides DS latency)
            bf16x8 sbn = *(const bf16x8*)&xs[wave * 64 + (((i + 1) & 3) * 16) + lr][32 + quad * 8];
            f32x4 acc0 = binit0, acc1 = binit1;
            acc0 = __builtin_amdgcn_mfma_f32_16x16x32_bf16(gf0, sb, acc0, 0, 0, 0);
            acc1 = __builtin_amdgcn_mfma_f32_16x16x32_bf16(gf1, sb, acc1, 0, 0, 0);
            // L2 partials: lane owns row m=lr, 8 g-values
            float lg[8];
            #pragma unroll
            for (int e = 0; e < 8; ++e) lg[e] = gb2q[e];
            #pragma unroll
            for (int r = 0; r < 4; ++r) {
                float v = fmaxf(acc0[r], 0.f);
                #pragma unroll
                for (int e = 0; e < 8; ++e) lg[e] = fmaf(v, gw2r[r][e], lg[e]);
            }
            #pragma unroll
            for (int r = 0; r < 4; ++r) {
                float v = fmaxf(acc1[r], 0.f);
                #pragma unroll
                for (int e = 0; e < 8; ++e) lg[e] = fmaf(v, gw2r[4 + r][e], lg[e]);
            }
            // reduce partials across the 4 quads (xor16 then xor32)
            #pragma unroll
            for (int e = 0; e < 8; ++e) {
                float v = bperm_add(lg[e], a16);
                lg[e] = bperm_add(v, a32);
            }
            // softmax (16 rows in parallel across lr lanes; quads redundant)
            float mx = fmaxf(fmaxf(fmaxf(lg[0], lg[1]), fmaxf(lg[2], lg[3])),
                             fmaxf(fmaxf(lg[4], lg[5]), fmaxf(lg[6], lg[7])));
            float pv[8], sum = 0.f;
            #pragma unroll
            for (int e = 0; e < 8; ++e) { pv[e] = __expf(lg[e] - mx); sum += pv[e]; }
            const float inv = __builtin_amdgcn_rcpf(sum);
            if (quad == 0) {
                uint4 u;
                u.x = pk2(pv[0] * inv, pv[1] * inv);
                u.y = pk2(pv[2] * inv, pv[3] * inv);
                u.z = pk2(pv[4] * inv, pv[5] * inv);
                u.w = pk2(pv[6] * inv, pv[7] * inv);
                *(uint4*)&psb[rt * 16 + lr][0] = u;
            }
            sb = sbn;
        }
    }

    // ---- Load expert W1^T A-frags + contiguous per-(tt,quad) w2/b1 f32x4 ----
    bf16x8 blo[8], bhi[8];
    f32x4 w2q[8], b1q[8];
    const int e0 = wave * 2;
    #pragma unroll
    for (int tt = 0; tt < 8; ++tt) {
        const short* base = wf + ((size_t)((wave * 8 + tt) * 128) + lane) * 8;
        blo[tt] = *(const bf16x8*)base;
        bhi[tt] = *(const bf16x8*)(base + 512);
        const int nb = wave * 128 + tt * 16 + quad * 4;  // flat [E][H] index
        w2q[tt] = *(const f32x4*)(ew2 + nb);
        b1q[tt] = *(const f32x4*)(eb1 + nb);
    }
    const float pei0 = eb2[e0] * 0.25f;          // eb2 folded into per-quad partial init
    const float pei1 = eb2[e0 + 1] * 0.25f;      // (4 quads sum to eb2[e])

    __syncthreads();

    // ---- Phase 2: expert MFMA, transposed (eh^T = W1^T · x^T) ----
    // C/D: col = batch row (lr), row = n-within-tile (quad*4+r)
    // -> lane owns batch row rt*16+lr fully; h-reduce = per-lane FMA + 2 bperm.
    // Manual pipeline: tile rt+1's LDS reads issue during tile rt's MFMA+epilogue.
    bf16x8 xlo = *(const bf16x8*)&xs[lr][quad * 8];
    bf16x8 xhi = *(const bf16x8*)&xs[lr][quad * 8 + 32];
    unsigned pp = *(const unsigned*)&psb[lr][e0];

    #pragma unroll 1
    for (int rt = 0; rt < ROWS / 16; ++rt) {
        const int rn = ((rt + 1) & 15) * 16 + lr;   // next tile row (wraps, harmless)
        bf16x8 xlo_n = *(const bf16x8*)&xs[rn][quad * 8];
        bf16x8 xhi_n = *(const bf16x8*)&xs[rn][quad * 8 + 32];
        unsigned pp_n = *(const unsigned*)&psb[rn][e0];

        f32x4 acc[8];
        #pragma unroll
        for (int tt = 0; tt < 8; ++tt)            // b1 pre-loaded into accumulator
            acc[tt] = b1q[tt];
        #pragma unroll
        for (int tt = 0; tt < 8; ++tt)
            acc[tt] = __builtin_amdgcn_mfma_f32_16x16x32_bf16(blo[tt], xlo, acc[tt], 0, 0, 0);
        #pragma unroll
        for (int tt = 0; tt < 8; ++tt)
            acc[tt] = __builtin_amdgcn_mfma_f32_16x16x32_bf16(bhi[tt], xhi, acc[tt], 0, 0, 0);

        // epilogue: relu + w2 fold; 4 independent 8-deep chains (latency halved)
        float q0 = pei0, q1 = 0.f, q2 = pei1, q3 = 0.f;
        #pragma unroll
        for (int tt = 0; tt < 2; ++tt) {
            #pragma unroll
            for (int r = 0; r < 4; ++r) {
                q0 = fmaf(fmaxf(acc[tt][r],     0.0f), w2q[tt][r],     q0);
                q1 = fmaf(fmaxf(acc[tt + 2][r], 0.0f), w2q[tt + 2][r], q1);
                q2 = fmaf(fmaxf(acc[tt + 4][r], 0.0f), w2q[tt + 4][r], q2);
                q3 = fmaf(fmaxf(acc[tt + 6][r], 0.0f), w2q[tt + 6][r], q3);
            }
        }
        const float pe0 = q0 + q1, pe1 = q2 + q3;
        // gating probs: one dword holds both bf16 probs for this wave's experts
        const float p0 = __builtin_bit_cast(float, pp << 16);
        const float p1 = __builtin_bit_cast(float, pp & 0xffff0000u);
        float c = fmaf(pe0, p0, pe1 * p1);
        c = bperm_add(c, a16);                    // sum the 4 quads' h-slices
        c = bperm_add(c, a32);
        if (quad == 0) *(float*)&xs[rt * 16 + lr][64 + 2 * wave] = c;  // private slot

        xlo = xlo_n; xhi = xhi_n; pp = pp_n;
    }

    __syncthreads();
    const float4 fs = *(const float4*)&xs[t][64];
    out[row0 + t] = (fs.x + fs.y) + (fs.z + fs.w);
}

extern "C" void kernel_launch(void* const* d_in, const int* in_sizes, int n_in,
                              void* d_out, int out_size, void* d_ws, size_t ws_size,
                              hipStream_t stream) {
    const float* A   = (const float*)d_in[0];
    const float* S   = (const float*)d_in[1];
    const float* gw1 = (const float*)d_in[2];
    const float* gb1 = (const float*)d_in[3];
    const float* gw2 = (const float*)d_in[4];
    const float* gb2 = (const float*)d_in[5];
    const float* ew1 = (const float*)d_in[6];
    const float* eb1 = (const float*)d_in[7];
    const float* ew2 = (const float*)d_in[8];
    const float* eb2 = (const float*)d_in[9];
    float* out = (float*)d_out;
    short* wf = (short*)d_ws;   // 64 KB expert W1 frags + 2 KB gating gw1^T frags

    const int B = in_sizes[0] / 32;
    hipLaunchKernelGGL(prep_kernel, dim3(16), dim3(256), 0, stream, ew1, gw1, wf);
    hipLaunchKernelGGL(moe_kernel, dim3(B / ROWS), dim3(256), 0, stream,
                       A, S, gb1, gw2, gb2, wf, eb1, ew2, eb2, out);
}

// Round 7
// 190.355 us; speedup vs baseline: 1.2505x; 1.2505x over previous
//
#include <hip/hip_runtime.h>
#include <hip/hip_bf16.h>
#include <math.h>

#define ROWS 256
#define DD 64
#define EE 8
#define HH 64
#define GHD 32
#define XST 88   // xs row stride in shorts: 176 B, 16B-aligned, 2-way-max bank pattern

typedef __attribute__((ext_vector_type(8))) short bf16x8;
typedef __attribute__((ext_vector_type(4))) float f32x4;

static __device__ __forceinline__ short f2bf(float f) {
    unsigned u = __builtin_bit_cast(unsigned, f);
    unsigned r = (u + 0x7fffu + ((u >> 16) & 1u)) >> 16;  // round-to-nearest-even
    return (short)r;
}
static __device__ __forceinline__ float bf2f(unsigned short b) {
    unsigned u = ((unsigned)b) << 16;
    return __builtin_bit_cast(float, u);
}
// packed f32x2 -> bf16x2 (lowers to v_cvt_pk_bf16_f32, RNE — bit-identical to f2bf)
static __device__ __forceinline__ unsigned pk2(float lo, float hi) {
    __hip_bfloat162 h = __float22bfloat162_rn(make_float2(lo, hi));
    unsigned r;
    __builtin_memcpy(&r, &h, 4);
    return r;
}
// cross-lane add via ds_bpermute (addr = (lane^mask)<<2, precomputed)
static __device__ __forceinline__ float bperm_add(float x, int addr) {
    int xi = __builtin_bit_cast(int, x);
    int yi = __builtin_amdgcn_ds_bpermute(addr, xi);
    return x + __builtin_bit_cast(float, yi);
}

// Precompute W1 (experts) and gw1 (gating) as bf16 MFMA fragments in d_ws.
// For 16x16x32, A-frag and B-frag lane->(index,k) maps are identical, so these
// frags serve as W1 B-operand (x·W1) or W1^T A-operand (W1^T·x^T) unchanged.
// expert frags: flat idx = nt*128 + half*64 + lane (nt = n-tile 0..31), 8 shorts each (64 KB)
// gating frags (gw1^T A-operand): 2 tiles x 64 lanes x 8 shorts at short-offset 32768 (2 KB)
// d_ws must be >= 67584 bytes.
__global__ __launch_bounds__(256) void prep_kernel(const float* __restrict__ ew1,
                                                   const float* __restrict__ gw1,
                                                   short* __restrict__ wf) {
    int idx = blockIdx.x * 256 + threadIdx.x;   // 4096 frags
    int lane = idx & 63;
    int half = (idx >> 6) & 1;
    int nt   = (idx >> 7) & 31;                 // n-tile: n in [nt*16, nt*16+16)
    int n = nt * 16 + (lane & 15);
    int e = n >> 6, h = n & 63;
    int quad = lane >> 4;
    short v[8];
    #pragma unroll
    for (int j = 0; j < 8; ++j) {
        int dl = quad * 8 + j + half * 32;
        v[j] = f2bf(ew1[(e * DD + dl) * HH + h]);
    }
    *(bf16x8*)(wf + (size_t)idx * 8) = *(const bf16x8*)v;
    if (idx < 128) {                            // gw1^T A-frags
        int tile = idx >> 6;
        int lr = lane & 15;
        short g[8];
        #pragma unroll
        for (int j = 0; j < 8; ++j)
            g[j] = f2bf(gw1[(quad * 8 + j) * GHD + tile * 16 + lr]);
        *(bf16x8*)(wf + 32768 + (size_t)idx * 8) = *(const bf16x8*)g;
    }
}

// 512 threads = 8 waves; wave w owns expert w in phase 2, rows [w*32, w*32+32) in gating.
__global__ __launch_bounds__(512, 3) void moe_kernel(
    const float* __restrict__ A, const float* __restrict__ S,
    const float* __restrict__ gb1, const float* __restrict__ gw2,
    const float* __restrict__ gb2, const short* __restrict__ wf,
    const float* __restrict__ eb1, const float* __restrict__ ew2,
    const float* __restrict__ eb2, float* __restrict__ out)
{
    // xs row = 88 shorts (176 B): [0..63] bf16 x-data, [64..79] = 8 f32 result slots (1/wave).
    __shared__ __align__(16) short xs[ROWS][XST];           // 45056 B
    __shared__ __align__(16) unsigned short psb[ROWS][EE];  // 4096 B (bf16 gating probs)
    // total 49152 B

    const int t = threadIdx.x;
    const int row0 = blockIdx.x * ROWS;
    const int lane = t & 63;
    const int wave = t >> 6;
    const int quad = lane >> 4;
    const int lr = lane & 15;

    // ---- Phase 1: x -> bf16 LDS; 2 threads per row (even: A-half, odd: S-half) ----
    {
        const int row = t >> 1;
        const int half = t & 1;
        const float4* src = (const float4*)((half ? S : A) + (size_t)(row0 + row) * 32);
        #pragma unroll
        for (int i = 0; i < 4; ++i) {
            float4 v0 = src[2 * i], v1 = src[2 * i + 1];
            uint4 u;
            u.x = pk2(v0.x, v0.y); u.y = pk2(v0.z, v0.w);
            u.z = pk2(v1.x, v1.y); u.w = pk2(v1.z, v1.w);
            *(uint4*)&xs[row][half * 32 + i * 8] = u;
        }
    }
    // Wave-local ordering: wave w's 64 lanes wrote rows [w*32, w*32+32); gating below
    // reads exactly those rows -> no __syncthreads needed, but the cross-lane LDS
    // writes must drain before any read (rule #18).
    asm volatile("s_waitcnt lgkmcnt(0)" ::: "memory");
    __builtin_amdgcn_sched_barrier(0);

    const int a16 = (lane ^ 16) << 2;
    const int a32 = (lane ^ 32) << 2;

    // ---- Phase 1.5: gating, transposed (gh^T = gw1^T · S^T), register-only ----
    {
        const short* gwf = wf + 32768;
        bf16x8 gf0 = *(const bf16x8*)(gwf + (size_t)lane * 8);         // gw1^T rows g=0..15
        bf16x8 gf1 = *(const bf16x8*)(gwf + 512 + (size_t)lane * 8);   // rows g=16..31
        // per-lane gw2 slice: rows g = quad*4+j (j<4) and 16+quad*4+(j-4) (j>=4)
        float gw2r[8][8];
        #pragma unroll
        for (int j = 0; j < 4; ++j) {
            float4 a0 = *(const float4*)(gw2 + (quad * 4 + j) * 8);
            float4 a1 = *(const float4*)(gw2 + (quad * 4 + j) * 8 + 4);
            gw2r[j][0] = a0.x; gw2r[j][1] = a0.y; gw2r[j][2] = a0.z; gw2r[j][3] = a0.w;
            gw2r[j][4] = a1.x; gw2r[j][5] = a1.y; gw2r[j][6] = a1.z; gw2r[j][7] = a1.w;
            float4 b0 = *(const float4*)(gw2 + (16 + quad * 4 + j) * 8);
            float4 b1 = *(const float4*)(gw2 + (16 + quad * 4 + j) * 8 + 4);
            gw2r[4 + j][0] = b0.x; gw2r[4 + j][1] = b0.y; gw2r[4 + j][2] = b0.z; gw2r[4 + j][3] = b0.w;
            gw2r[4 + j][4] = b1.x; gw2r[4 + j][5] = b1.y; gw2r[4 + j][6] = b1.z; gw2r[4 + j][7] = b1.w;
        }
        const f32x4 binit0 = *(const f32x4*)(gb1 + quad * 4);
        const f32x4 binit1 = *(const f32x4*)(gb1 + 16 + quad * 4);
        // gb2 folded into quad-0's partial init: the xor16/xor32 butterfly
        // distributes the full sum (incl. gb2) to every lane.
        float gb2q[8];
        #pragma unroll
        for (int e = 0; e < 8; ++e) gb2q[e] = (quad == 0) ? gb2[e] : 0.0f;

        #pragma unroll 1
        for (int i = 0; i < 2; ++i) {
            const int rt = wave * 2 + i;
            // B-frag = S^T: identical bytes/layout to a row A-frag read
            bf16x8 sb = *(const bf16x8*)&xs[rt * 16 + lr][32 + quad * 8];
            f32x4 acc0 = binit0, acc1 = binit1;
            acc0 = __builtin_amdgcn_mfma_f32_16x16x32_bf16(gf0, sb, acc0, 0, 0, 0);
            acc1 = __builtin_amdgcn_mfma_f32_16x16x32_bf16(gf1, sb, acc1, 0, 0, 0);
            // L2 partials: lane owns row m=lr, 8 g-values
            float lg[8];
            #pragma unroll
            for (int e = 0; e < 8; ++e) lg[e] = gb2q[e];
            #pragma unroll
            for (int r = 0; r < 4; ++r) {
                float v = fmaxf(acc0[r], 0.f);
                #pragma unroll
                for (int e = 0; e < 8; ++e) lg[e] = fmaf(v, gw2r[r][e], lg[e]);
            }
            #pragma unroll
            for (int r = 0; r < 4; ++r) {
                float v = fmaxf(acc1[r], 0.f);
                #pragma unroll
                for (int e = 0; e < 8; ++e) lg[e] = fmaf(v, gw2r[4 + r][e], lg[e]);
            }
            // reduce partials across the 4 quads (xor16 then xor32)
            #pragma unroll
            for (int e = 0; e < 8; ++e) {
                float v = bperm_add(lg[e], a16);
                lg[e] = bperm_add(v, a32);
            }
            // softmax (16 rows in parallel across lr lanes; quads redundant)
            float mx = fmaxf(fmaxf(fmaxf(lg[0], lg[1]), fmaxf(lg[2], lg[3])),
                             fmaxf(fmaxf(lg[4], lg[5]), fmaxf(lg[6], lg[7])));
            float pv[8], sum = 0.f;
            #pragma unroll
            for (int e = 0; e < 8; ++e) { pv[e] = __expf(lg[e] - mx); sum += pv[e]; }
            const float inv = __builtin_amdgcn_rcpf(sum);
            if (quad == 0) {
                uint4 u;
                u.x = pk2(pv[0] * inv, pv[1] * inv);
                u.y = pk2(pv[2] * inv, pv[3] * inv);
                u.z = pk2(pv[4] * inv, pv[5] * inv);
                u.w = pk2(pv[6] * inv, pv[7] * inv);
                *(uint4*)&psb[rt * 16 + lr][0] = u;
            }
        }
    }

    // ---- Load this wave's expert frags (n in [wave*64, wave*64+64)) + w2/b1 ----
    bf16x8 blo[4], bhi[4];
    f32x4 w2q[4], b1q[4];
    #pragma unroll
    for (int tt = 0; tt < 4; ++tt) {
        const short* base = wf + ((size_t)((wave * 4 + tt) * 128) + lane) * 8;
        blo[tt] = *(const bf16x8*)base;
        bhi[tt] = *(const bf16x8*)(base + 512);
        const int nb = wave * 64 + tt * 16 + quad * 4;   // flat [E][H] index
        w2q[tt] = *(const f32x4*)(ew2 + nb);
        b1q[tt] = *(const f32x4*)(eb1 + nb);
    }
    const float pei = eb2[wave] * 0.25f;   // eb2 folded into per-quad partial init

    __syncthreads();

    // ---- Phase 2: expert MFMA, transposed (eh^T = W1^T · x^T), 1 expert/wave ----
    // C/D: col = batch row (lr), row = n-within-tile (quad*4+r)
    // -> lane owns batch row rt*16+lr; h-reduce = per-lane FMA + 2 bperm.
    #pragma unroll 1
    for (int rt = 0; rt < ROWS / 16; ++rt) {
        const short* xp = &xs[rt * 16 + lr][quad * 8];
        bf16x8 xlo = *(const bf16x8*)xp;          // d in [0,32)
        bf16x8 xhi = *(const bf16x8*)(xp + 32);   // d in [32,64)
        f32x4 acc[4];
        #pragma unroll
        for (int tt = 0; tt < 4; ++tt)            // b1 pre-loaded into accumulator
            acc[tt] = b1q[tt];
        #pragma unroll
        for (int tt = 0; tt < 4; ++tt)
            acc[tt] = __builtin_amdgcn_mfma_f32_16x16x32_bf16(blo[tt], xlo, acc[tt], 0, 0, 0);
        #pragma unroll
        for (int tt = 0; tt < 4; ++tt)
            acc[tt] = __builtin_amdgcn_mfma_f32_16x16x32_bf16(bhi[tt], xhi, acc[tt], 0, 0, 0);

        // epilogue: relu + w2 fold; 2 independent 8-deep chains
        float q0 = pei, q1 = 0.f;
        #pragma unroll
        for (int tt = 0; tt < 2; ++tt) {
            #pragma unroll
            for (int r = 0; r < 4; ++r) {
                q0 = fmaf(fmaxf(acc[tt][r],     0.0f), w2q[tt][r],     q0);
                q1 = fmaf(fmaxf(acc[tt + 2][r], 0.0f), w2q[tt + 2][r], q1);
            }
        }
        const float p = bf2f(psb[rt * 16 + lr][wave]);
        float c = (q0 + q1) * p;
        c = bperm_add(c, a16);                    // sum the 4 quads' h-slices
        c = bperm_add(c, a32);
        if (quad == 0) *(float*)&xs[rt * 16 + lr][64 + 2 * wave] = c;  // private slot
    }

    __syncthreads();
    if (t < ROWS) {
        const float4 f0 = *(const float4*)&xs[t][64];
        const float4 f1 = *(const float4*)&xs[t][72];
        out[row0 + t] = ((f0.x + f0.y) + (f0.z + f0.w)) + ((f1.x + f1.y) + (f1.z + f1.w));
    }
}

extern "C" void kernel_launch(void* const* d_in, const int* in_sizes, int n_in,
                              void* d_out, int out_size, void* d_ws, size_t ws_size,
                              hipStream_t stream) {
    const float* A   = (const float*)d_in[0];
    const float* S   = (const float*)d_in[1];
    const float* gw1 = (const float*)d_in[2];
    const float* gb1 = (const float*)d_in[3];
    const float* gw2 = (const float*)d_in[4];
    const float* gb2 = (const float*)d_in[5];
    const float* ew1 = (const float*)d_in[6];
    const float* eb1 = (const float*)d_in[7];
    const float* ew2 = (const float*)d_in[8];
    const float* eb2 = (const float*)d_in[9];
    float* out = (float*)d_out;
    short* wf = (short*)d_ws;   // 64 KB expert W1 frags + 2 KB gating gw1^T frags

    const int B = in_sizes[0] / 32;
    hipLaunchKernelGGL(prep_kernel, dim3(16), dim3(256), 0, stream, ew1, gw1, wf);
    hipLaunchKernelGGL(moe_kernel, dim3(B / ROWS), dim3(512), 0, stream,
                       A, S, gb1, gw2, gb2, wf, eb1, ew2, eb2, out);
}

// Round 9
// 186.278 us; speedup vs baseline: 1.2779x; 1.0219x over previous
//
#include <hip/hip_runtime.h>
#include <hip/hip_bf16.h>
#include <math.h>

#define ROWS 256
#define DD 64
#define EE 8
#define HH 64
#define GHD 32
#define XST 88   // xs row stride in shorts: 176 B, 16B-aligned, 2-way-max bank pattern

typedef __attribute__((ext_vector_type(8))) short bf16x8;
typedef __attribute__((ext_vector_type(4))) float f32x4;
typedef __attribute__((ext_vector_type(2))) float f32x2;

static __device__ __forceinline__ short f2bf(float f) {
    unsigned u = __builtin_bit_cast(unsigned, f);
    unsigned r = (u + 0x7fffu + ((u >> 16) & 1u)) >> 16;  // round-to-nearest-even
    return (short)r;
}
static __device__ __forceinline__ float bf2f(unsigned short b) {
    unsigned u = ((unsigned)b) << 16;
    return __builtin_bit_cast(float, u);
}
// packed f32x2 -> bf16x2 (lowers to v_cvt_pk_bf16_f32, RNE — bit-identical to f2bf)
static __device__ __forceinline__ unsigned pk2(float lo, float hi) {
    __hip_bfloat162 h = __float22bfloat162_rn(make_float2(lo, hi));
    unsigned r;
    __builtin_memcpy(&r, &h, 4);
    return r;
}
// cross-lane add via ds_bpermute (addr = (lane^mask)<<2, precomputed)
static __device__ __forceinline__ float bperm_add(float x, int addr) {
    int xi = __builtin_bit_cast(int, x);
    int yi = __builtin_amdgcn_ds_bpermute(addr, xi);
    return x + __builtin_bit_cast(float, yi);
}
// packed helpers (lower to v_pk_max_f32 / v_pk_fma_f32)
static __device__ __forceinline__ f32x2 pmax0(f32x2 a) {
    return __builtin_elementwise_max(a, (f32x2){0.f, 0.f});
}
static __device__ __forceinline__ f32x2 pfma(f32x2 a, f32x2 b, f32x2 c) {
    return __builtin_elementwise_fma(a, b, c);
}

// Precompute W1 (experts) and gw1 (gating) as bf16 MFMA fragments in d_ws.
// For 16x16x32, A-frag and B-frag lane->(index,k) maps are identical, so these
// frags serve as W1 B-operand (x·W1) or W1^T A-operand (W1^T·x^T) unchanged.
// expert frags: flat idx = nt*128 + half*64 + lane (nt = n-tile 0..31), 8 shorts each (64 KB)
// gating frags (gw1^T A-operand): 2 tiles x 64 lanes x 8 shorts at short-offset 32768 (2 KB)
// d_ws must be >= 67584 bytes.
__global__ __launch_bounds__(256) void prep_kernel(const float* __restrict__ ew1,
                                                   const float* __restrict__ gw1,
                                                   short* __restrict__ wf) {
    int idx = blockIdx.x * 256 + threadIdx.x;   // 4096 frags
    int lane = idx & 63;
    int half = (idx >> 6) & 1;
    int nt   = (idx >> 7) & 31;                 // n-tile: n in [nt*16, nt*16+16)
    int n = nt * 16 + (lane & 15);
    int e = n >> 6, h = n & 63;
    int quad = lane >> 4;
    short v[8];
    #pragma unroll
    for (int j = 0; j < 8; ++j) {
        int dl = quad * 8 + j + half * 32;
        v[j] = f2bf(ew1[(e * DD + dl) * HH + h]);
    }
    *(bf16x8*)(wf + (size_t)idx * 8) = *(const bf16x8*)v;
    if (idx < 128) {                            // gw1^T A-frags
        int tile = idx >> 6;
        int lr = lane & 15;
        short g[8];
        #pragma unroll
        for (int j = 0; j < 8; ++j)
            g[j] = f2bf(gw1[(quad * 8 + j) * GHD + tile * 16 + lr]);
        *(bf16x8*)(wf + 32768 + (size_t)idx * 8) = *(const bf16x8*)g;
    }
}

// 512 threads = 8 waves; wave w owns expert w in phase 2, rows [w*32, w*32+32) in gating.
__global__ __launch_bounds__(512, 3) void moe_kernel(
    const float* __restrict__ A, const float* __restrict__ S,
    const float* __restrict__ gb1, const float* __restrict__ gw2,
    const float* __restrict__ gb2, const short* __restrict__ wf,
    const float* __restrict__ eb1, const float* __restrict__ ew2,
    const float* __restrict__ eb2, float* __restrict__ out)
{
    // xs row = 88 shorts (176 B): [0..63] bf16 x-data, [64..79] = 8 f32 result slots (1/wave).
    __shared__ __align__(16) short xs[ROWS][XST];           // 45056 B
    __shared__ __align__(16) unsigned short psb[ROWS][EE];  // 4096 B (bf16 gating probs)
    // total 49152 B

    const int t = threadIdx.x;
    const int row0 = blockIdx.x * ROWS;
    const int lane = t & 63;
    const int wave = t >> 6;
    const int quad = lane >> 4;
    const int lr = lane & 15;

    // ---- Phase 1: x -> bf16 LDS; 2 threads per row (even: A-half, odd: S-half) ----
    {
        const int row = t >> 1;
        const int half = t & 1;
        const float4* src = (const float4*)((half ? S : A) + (size_t)(row0 + row) * 32);
        #pragma unroll
        for (int i = 0; i < 4; ++i) {
            float4 v0 = src[2 * i], v1 = src[2 * i + 1];
            uint4 u;
            u.x = pk2(v0.x, v0.y); u.y = pk2(v0.z, v0.w);
            u.z = pk2(v1.x, v1.y); u.w = pk2(v1.z, v1.w);
            *(uint4*)&xs[row][half * 32 + i * 8] = u;
        }
    }
    // Wave-local ordering: wave w's 64 lanes wrote rows [w*32, w*32+32); gating below
    // reads exactly those rows -> no __syncthreads needed, but the cross-lane LDS
    // writes must drain before any read (rule #18).
    asm volatile("s_waitcnt lgkmcnt(0)" ::: "memory");
    __builtin_amdgcn_sched_barrier(0);

    const int a16 = (lane ^ 16) << 2;
    const int a32 = (lane ^ 32) << 2;

    // ---- Phase 1.5: gating, transposed (gh^T = gw1^T · S^T), register-only ----
    // (kept fully scalar — the R8 packed version of this phase failed absmax)
    {
        const short* gwf = wf + 32768;
        bf16x8 gf0 = *(const bf16x8*)(gwf + (size_t)lane * 8);         // gw1^T rows g=0..15
        bf16x8 gf1 = *(const bf16x8*)(gwf + 512 + (size_t)lane * 8);   // rows g=16..31
        // per-lane gw2 slice: rows g = quad*4+j (j<4) and 16+quad*4+(j-4) (j>=4)
        float gw2r[8][8];
        #pragma unroll
        for (int j = 0; j < 4; ++j) {
            float4 a0 = *(const float4*)(gw2 + (quad * 4 + j) * 8);
            float4 a1 = *(const float4*)(gw2 + (quad * 4 + j) * 8 + 4);
            gw2r[j][0] = a0.x; gw2r[j][1] = a0.y; gw2r[j][2] = a0.z; gw2r[j][3] = a0.w;
            gw2r[j][4] = a1.x; gw2r[j][5] = a1.y; gw2r[j][6] = a1.z; gw2r[j][7] = a1.w;
            float4 b0 = *(const float4*)(gw2 + (16 + quad * 4 + j) * 8);
            float4 b1 = *(const float4*)(gw2 + (16 + quad * 4 + j) * 8 + 4);
            gw2r[4 + j][0] = b0.x; gw2r[4 + j][1] = b0.y; gw2r[4 + j][2] = b0.z; gw2r[4 + j][3] = b0.w;
            gw2r[4 + j][4] = b1.x; gw2r[4 + j][5] = b1.y; gw2r[4 + j][6] = b1.z; gw2r[4 + j][7] = b1.w;
        }
        const f32x4 binit0 = *(const f32x4*)(gb1 + quad * 4);
        const f32x4 binit1 = *(const f32x4*)(gb1 + 16 + quad * 4);
        // gb2 folded into quad-0's partial init: the xor16/xor32 butterfly
        // distributes the full sum (incl. gb2) to every lane.
        float gb2q[8];
        #pragma unroll
        for (int e = 0; e < 8; ++e) gb2q[e] = (quad == 0) ? gb2[e] : 0.0f;

        #pragma unroll 1
        for (int i = 0; i < 2; ++i) {
            const int rt = wave * 2 + i;
            // B-frag = S^T: identical bytes/layout to a row A-frag read
            bf16x8 sb = *(const bf16x8*)&xs[rt * 16 + lr][32 + quad * 8];
            // bias rides in as the C operand (D != C, no init copies)
            f32x4 acc0 = __builtin_amdgcn_mfma_f32_16x16x32_bf16(gf0, sb, binit0, 0, 0, 0);
            f32x4 acc1 = __builtin_amdgcn_mfma_f32_16x16x32_bf16(gf1, sb, binit1, 0, 0, 0);
            // L2 partials: lane owns row m=lr, 8 g-values
            float lg[8];
            #pragma unroll
            for (int e = 0; e < 8; ++e) lg[e] = gb2q[e];
            #pragma unroll
            for (int r = 0; r < 4; ++r) {
                float v = fmaxf(acc0[r], 0.f);
                #pragma unroll
                for (int e = 0; e < 8; ++e) lg[e] = fmaf(v, gw2r[r][e], lg[e]);
            }
            #pragma unroll
            for (int r = 0; r < 4; ++r) {
                float v = fmaxf(acc1[r], 0.f);
                #pragma unroll
                for (int e = 0; e < 8; ++e) lg[e] = fmaf(v, gw2r[4 + r][e], lg[e]);
            }
            // reduce partials across the 4 quads (xor16 then xor32)
            #pragma unroll
            for (int e = 0; e < 8; ++e) {
                float v = bperm_add(lg[e], a16);
                lg[e] = bperm_add(v, a32);
            }
            // softmax (16 rows in parallel across lr lanes; quads redundant)
            float mx = fmaxf(fmaxf(fmaxf(lg[0], lg[1]), fmaxf(lg[2], lg[3])),
                             fmaxf(fmaxf(lg[4], lg[5]), fmaxf(lg[6], lg[7])));
            float pv[8], sum = 0.f;
            #pragma unroll
            for (int e = 0; e < 8; ++e) { pv[e] = __expf(lg[e] - mx); sum += pv[e]; }
            const float inv = __builtin_amdgcn_rcpf(sum);
            if (quad == 0) {
                uint4 u;
                u.x = pk2(pv[0] * inv, pv[1] * inv);
                u.y = pk2(pv[2] * inv, pv[3] * inv);
                u.z = pk2(pv[4] * inv, pv[5] * inv);
                u.w = pk2(pv[6] * inv, pv[7] * inv);
                *(uint4*)&psb[rt * 16 + lr][0] = u;
            }
        }
    }

    // ---- Load this wave's expert frags (n in [wave*64, wave*64+64)) + w2/b1 ----
    bf16x8 blo[4], bhi[4];
    f32x2 w2p2[4][2];
    f32x4 b1q[4];
    #pragma unroll
    for (int tt = 0; tt < 4; ++tt) {
        const short* base = wf + ((size_t)((wave * 4 + tt) * 128) + lane) * 8;
        blo[tt] = *(const bf16x8*)base;
        bhi[tt] = *(const bf16x8*)(base + 512);
        const int nb = wave * 64 + tt * 16 + quad * 4;   // flat [E][H] index
        float4 w = *(const float4*)(ew2 + nb);
        w2p2[tt][0] = (f32x2){w.x, w.y};
        w2p2[tt][1] = (f32x2){w.z, w.w};
        b1q[tt] = *(const f32x4*)(eb1 + nb);
    }
    const float pei = eb2[wave] * 0.25f;   // eb2 folded into per-quad partial init

    __syncthreads();

    // ---- Phase 2: expert MFMA, transposed (eh^T = W1^T · x^T), 1 expert/wave ----
    // C/D: col = batch row (lr), row = n-within-tile (quad*4+r)
    // -> lane owns batch row rt*16+lr; h-reduce = per-lane packed FMA + 2 bperm.
    #pragma unroll 1
    for (int rt = 0; rt < ROWS / 16; ++rt) {
        const short* xp = &xs[rt * 16 + lr][quad * 8];
        bf16x8 xlo = *(const bf16x8*)xp;          // d in [0,32)
        bf16x8 xhi = *(const bf16x8*)(xp + 32);   // d in [32,64)
        f32x4 acc[4];
        #pragma unroll
        for (int tt = 0; tt < 4; ++tt)            // b1 rides in as C operand (no copies)
            acc[tt] = __builtin_amdgcn_mfma_f32_16x16x32_bf16(blo[tt], xlo, b1q[tt], 0, 0, 0);
        #pragma unroll
        for (int tt = 0; tt < 4; ++tt)
            acc[tt] = __builtin_amdgcn_mfma_f32_16x16x32_bf16(bhi[tt], xhi, acc[tt], 0, 0, 0);

        // epilogue: packed relu + w2 fold; same 16 terms as the scalar version,
        // paired (r0,r1)/(r2,r3): acc[tt][r] <-> ew2[wave*64+tt*16+quad*4+r]
        f32x2 qa = (f32x2){pei, 0.f};
        f32x2 qb = (f32x2){0.f, 0.f};
        #pragma unroll
        for (int tt = 0; tt < 4; ++tt) {
            f32x2 alo = (f32x2){acc[tt][0], acc[tt][1]};
            f32x2 ahi = (f32x2){acc[tt][2], acc[tt][3]};
            qa = pfma(pmax0(alo), w2p2[tt][0], qa);
            qb = pfma(pmax0(ahi), w2p2[tt][1], qb);
        }
        f32x2 qs = qa + qb;
        const float p = bf2f(psb[rt * 16 + lr][wave]);
        float c = (qs.x + qs.y) * p;
        c = bperm_add(c, a16);                    // sum the 4 quads' h-slices
        c = bperm_add(c, a32);
        if (quad == 0) *(float*)&xs[rt * 16 + lr][64 + 2 * wave] = c;  // private slot
    }

    __syncthreads();
    if (t < ROWS) {
        const float4 f0 = *(const float4*)&xs[t][64];
        const float4 f1 = *(const float4*)&xs[t][72];
        out[row0 + t] = ((f0.x + f0.y) + (f0.z + f0.w)) + ((f1.x + f1.y) + (f1.z + f1.w));
    }
}

extern "C" void kernel_launch(void* const* d_in, const int* in_sizes, int n_in,
                              void* d_out, int out_size, void* d_ws, size_t ws_size,
                              hipStream_t stream) {
    const float* A   = (const float*)d_in[0];
    const float* S   = (const float*)d_in[1];
    const float* gw1 = (const float*)d_in[2];
    const float* gb1 = (const float*)d_in[3];
    const float* gw2 = (const float*)d_in[4];
    const float* gb2 = (const float*)d_in[5];
    const float* ew1 = (const float*)d_in[6];
    const float* eb1 = (const float*)d_in[7];
    const float* ew2 = (const float*)d_in[8];
    const float* eb2 = (const float*)d_in[9];
    float* out = (float*)d_out;
    short* wf = (short*)d_ws;   // 64 KB expert W1 frags + 2 KB gating gw1^T frags

    const int B = in_sizes[0] / 32;
    hipLaunchKernelGGL(prep_kernel, dim3(16), dim3(256), 0, stream, ew1, gw1, wf);
    hipLaunchKernelGGL(moe_kernel, dim3(B / ROWS), dim3(512), 0, stream,
                       A, S, gb1, gw2, gb2, wf, eb1, ew2, eb2, out);
}